// Round 10
// baseline (49.595 us; speedup 1.0000x reference)
//
#include <hip/hip_runtime.h>

#define NB 128
#define NQ 1000
#define NG 300
#define NK 4
#define THRESH 0.4f

#define GCHUNKS  8                 // 8 x 38 = 304 >= 300 GT slots
#define GPERB    38                // GTs per block
#define NTHREADS 512               // 2 queries per thread
#define CAP      48                // per-GT candidate list capacity

// ---------------------------------------------------------------------------
// Single fused kernel, no workspace (d_ws re-poison costs ~39 us/replay).
//
// Consolidated structure lessons (r5..r9 A/B series):
//   * occupancy >= 8 waves/SIMD is mandatory (r8/r9 at 3-6 waves regressed;
//     the ~9-deep dependent FP chain needs the TLP);
//   * r5 (28us, best) was LDS-pipe-bound: 2 LDS reads per single test;
//   * full unroll of the GT loop (r9) suspected VGPR/spill pathology - avoid.
// This round = r5 + two surgical changes at r5's exact occupancy:
//   1 ds_read_b128 per TWO tests (2 query boxes/thread in registers), and
//   ta999 computed in registers instead of a second LDS read.
//   Grid (8,128)=1024 blocks = 4 blocks/CU x 8 waves = 32 waves/CU, pinned
//   via __launch_bounds__(512, 8).
//
// Phase 1 exact conservative prefilter: iou>0.4 <=> 3.5*inter > pa+ta,
// tested as fma(inter,3.5,-0.999pa) >= 0.999ta (0.1% margin >> f32 rounding
// => no true positive dropped; rare false positives in iou~[0.3997,0.4]
// removed by phase 2's exact math). Direct per-GT LDS atomic push (branch
// is SALU and ~2% taken -- proven cheap in r5).
// Phase 2 (8 lanes/GT): exact reference-identical math (full IEEE div, same
// epsilon/op order, sigmoid), top-4 via u64 keys (valbits<<32)|~q ==
// (value desc, index asc) = jax.lax.top_k order; bitonic merge masks 1,2,4
// (r6/r7-validated network); zero-filler indices = smallest unused q.
// Protocol validated absmax=0.0 in rounds 3-9.
// ---------------------------------------------------------------------------
__global__ __launch_bounds__(NTHREADS, 8) void fused_matcher(
    const float* __restrict__ logits,      // [B,Q,1]
    const float* __restrict__ pboxes,      // [B,Q,4]
    const float* __restrict__ tboxes,      // [B,G,4]
    float* __restrict__ out_vals,          // [B,G,K]
    float* __restrict__ out_idx,           // [B,G,K] (as float)
    float* __restrict__ out_mask)          // [B,G,K] (0/1 float)
{
    __shared__ float4 stb[GPERB + 1];                 // GT boxes (+sentinel)
    __shared__ unsigned scnt[GPERB];                  // per-GT counts
    __shared__ unsigned short sslot[GPERB][CAP];      // per-GT candidate q's

    const int b   = blockIdx.y;
    const int gc  = blockIdx.x;
    const int tid = threadIdx.x;
    const int g0  = gc * GPERB;
    const int ng  = (NG - g0 < GPERB) ? (NG - g0) : GPERB;

    const float4* __restrict__ tb4 =
        reinterpret_cast<const float4*>(tboxes) + (size_t)b * NG + g0;
    const float4* __restrict__ pb4 =
        reinterpret_cast<const float4*>(pboxes) + (size_t)b * NQ;

    // Dummy GT: zero area (ta999=0) and far corner => inter=0 with any real
    // query => test -qa999>=0 false. Dummy query: inverted far box => qa999
    // ~ +1.6e19 => never passes even vs dummy GT (0 >= 0 avoided).
    const float4 dummyG = make_float4(2e9f, 2e9f, 2e9f, 2e9f);
    const float4 dummyQ = make_float4(2e9f, 2e9f, -2e9f, -2e9f);

    // ---- Stage: GT boxes to LDS; 2 query boxes to registers. ----
    if (tid < GPERB) {
        stb[tid]  = (tid < ng) ? tb4[tid] : dummyG;
        scnt[tid] = 0u;
    }
    if (tid == GPERB) stb[GPERB] = dummyG;

    float4 pA = pb4[tid];                                  // q = tid (<512)
    float4 pB = (NTHREADS + tid < NQ) ? pb4[NTHREADS + tid] : dummyQ;
    const float qaA = 0.999f * ((pA.z - pA.x) * (pA.w - pA.y));
    const float qaB = 0.999f * ((pB.z - pB.x) * (pB.w - pB.y));

    __syncthreads();

    // ---- Phase 1: 38 iterations, 1 pipelined broadcast b128 per 2 tests;
    //      GT area computed in registers (no second LDS read). ----
    float4 tc = stb[0];
    for (int gi = 0; gi < GPERB; ++gi) {
        float4 tn = stb[gi + 1];   // prefetch next GT box (broadcast read)
        const float ta999 = 0.999f * ((tc.z - tc.x) * (tc.w - tc.y));

#define TEST(P, QA, QIDX)                                                   \
        {                                                                   \
            float ltx = fmaxf(P.x, tc.x);                                   \
            float lty = fmaxf(P.y, tc.y);                                   \
            float rbx = fminf(P.z, tc.z);                                   \
            float rby = fminf(P.w, tc.w);                                   \
            float w = fmaxf(rbx - ltx, 0.0f);                               \
            float h = fmaxf(rby - lty, 0.0f);                               \
            float inter = w * h;                                            \
            if (fmaf(inter, 3.5f, -(QA)) >= ta999) {                        \
                unsigned pos = atomicAdd(&scnt[gi], 1u);                    \
                if (pos < CAP)                                              \
                    sslot[gi][pos] = (unsigned short)(QIDX);                \
            }                                                               \
        }
        TEST(pA, qaA, tid)
        TEST(pB, qaB, NTHREADS + tid)
#undef TEST
        tc = tn;
    }
    __syncthreads();

    // ---- Phase 2: exact select, 8 lanes per GT. ----
    const int grp = tid >> 3;    // GT within chunk (0..63)
    const int l8  = tid & 7;
    if (grp < ng) {
        const float4 tb = stb[grp];
        const float tarea = (tb.z - tb.x) * (tb.w - tb.y);
        int n = (int)scnt[grp];
        if (n > CAP) n = CAP;
        const float* __restrict__ lg = logits + (size_t)b * NQ;

        unsigned long long k0 = 0ull, k1 = 0ull, k2 = 0ull, k3 = 0ull;
        for (int i = l8; i < n; i += 8) {
            const int q = sslot[grp][i];
            const float4 pp = pb4[q];
            float parea = (pp.z - pp.x) * (pp.w - pp.y);
            float ltx = fmaxf(pp.x, tb.x);
            float lty = fmaxf(pp.y, tb.y);
            float rbx = fminf(pp.z, tb.z);
            float rby = fminf(pp.w, tb.w);
            float w = fmaxf(rbx - ltx, 0.0f);
            float h = fmaxf(rby - lty, 0.0f);
            float inter = w * h;
            float uni   = parea + tarea - inter;
            float iou   = inter / (uni + 1e-7f);
            if (iou > THRESH) {
                float x   = lg[q];
                float sc  = 1.0f / (1.0f + expf(-x));
                float val = sc * iou;
                unsigned long long ck =
                    ((unsigned long long)__float_as_uint(val) << 32) |
                    (unsigned long long)(unsigned)(~(unsigned)q);
                if (ck > k3) {
                    if (ck > k0)      { k3 = k2; k2 = k1; k1 = k0; k0 = ck; }
                    else if (ck > k1) { k3 = k2; k2 = k1; k1 = ck; }
                    else if (ck > k2) { k3 = k2; k2 = ck; }
                    else              { k3 = ck; }
                }
            }
        }

        // Bitonic merge of sorted-4 lists across the 8-lane group.
#define MERGE_STEP(MASK)                                                    \
        {                                                                   \
            unsigned long long p0 = __shfl_xor(k0, MASK, 64);               \
            unsigned long long p1 = __shfl_xor(k1, MASK, 64);               \
            unsigned long long p2 = __shfl_xor(k2, MASK, 64);               \
            unsigned long long p3 = __shfl_xor(k3, MASK, 64);               \
            k0 = k0 > p3 ? k0 : p3;                                         \
            k1 = k1 > p2 ? k1 : p2;                                         \
            k2 = k2 > p1 ? k2 : p1;                                         \
            k3 = k3 > p0 ? k3 : p0;                                         \
            unsigned long long t;                                           \
            if (k0 < k2) { t = k0; k0 = k2; k2 = t; }                       \
            if (k1 < k3) { t = k1; k1 = k3; k3 = t; }                       \
            if (k0 < k1) { t = k0; k0 = k1; k1 = t; }                       \
            if (k2 < k3) { t = k2; k2 = k3; k3 = t; }                       \
        }
        MERGE_STEP(1)
        MERGE_STEP(2)
        MERGE_STEP(4)
#undef MERGE_STEP

        if (l8 == 0) {
            const int iq0 = k0 ? (int)~(unsigned)k0 : -1;
            const int iq1 = k1 ? (int)~(unsigned)k1 : -1;
            const int iq2 = k2 ? (int)~(unsigned)k2 : -1;
            float4 vv, vi, vm;
            float* pv = &vv.x; float* pi_ = &vi.x; float* pm = &vm.x;
            int fill = 0;
#define EMIT(J, KJ)                                                         \
            {                                                               \
                if (KJ != 0ull) {                                           \
                    pv[J]  = __uint_as_float((unsigned)(KJ >> 32));         \
                    pi_[J] = (float)(int)~(unsigned)KJ;                     \
                    pm[J]  = 1.0f;                                          \
                } else {                                                    \
                    while (fill == iq0 || fill == iq1 || fill == iq2)       \
                        ++fill;                                             \
                    pv[J]  = 0.0f;                                          \
                    pi_[J] = (float)fill;                                   \
                    pm[J]  = 0.0f;                                          \
                    ++fill;                                                 \
                }                                                           \
            }
            EMIT(0, k0) EMIT(1, k1) EMIT(2, k2) EMIT(3, k3)
#undef EMIT
            const size_t o4 = (size_t)b * NG + g0 + grp;  // float4 index
            reinterpret_cast<float4*>(out_vals)[o4] = vv;
            reinterpret_cast<float4*>(out_idx)[o4]  = vi;
            reinterpret_cast<float4*>(out_mask)[o4] = vm;
        }
    }
}

extern "C" void kernel_launch(void* const* d_in, const int* in_sizes, int n_in,
                              void* d_out, int out_size, void* d_ws, size_t ws_size,
                              hipStream_t stream) {
    const float* logits = (const float*)d_in[0];  // [128,1000,1]
    const float* pboxes = (const float*)d_in[1];  // [128,1000,4]
    const float* tboxes = (const float*)d_in[2];  // [128,300,4]

    float* out = (float*)d_out;
    const size_t bgk = (size_t)NB * NG * NK;      // 153600
    float* out_vals = out;
    float* out_idx  = out + bgk;
    float* out_mask = out + 2 * bgk;

    dim3 grid(GCHUNKS, NB);                       // (8,128) = 1024 blocks
    fused_matcher<<<grid, NTHREADS, 0, stream>>>(logits, pboxes, tboxes,
                                                 out_vals, out_idx, out_mask);
}